// Round 5
// baseline (163.880 us; speedup 1.0000x reference)
//
#include <hip/hip_runtime.h>
#include <math.h>

// Fused SelfAttention (attention over the HEADS axis, per token):
//   qkv = v @ [Wq|Wk|Wv]  (65536x256 @ 256x768, f16 MFMA)
//   per-token 8x8 softmax attention over heads (packed f16 + fp32 softmax)
//   out = x @ Wp + bp       (65536x256 @ 256x256, f16 MFMA)
//
// MFMA orientation: D = A*B, A = W^T-tile (rows = output col n), B = v^T-tile
// (cols = tokens). C/D layout: col(lane&15)=token, row(quad*4+r)=n.
//
// R5: TM=64 / 1024 threads / 1 block/CU. Halves the per-kernel L2 weight
// traffic (each block reads the full 512 KB packed-weight set exactly once;
// traffic = 512KB * #blocks). Separate v/x LDS region -> single-pass GEMM1,
// 3 barriers total. Depth-2 weight prefetch to cover ~200cyc L2 latency.

#define DIMX      256
#define NH        8
#define HD        32
#define TM        64       // tokens per block
#define NTHREADS  1024     // 16 waves
#define VSTRIDE   264      // f16 units; 528 B rows (16B aligned)
#define QSTRIDE   776      // f16 units; 1552 B rows (16B aligned)
#define KT        8        // 256/32 k-tiles
#define NT_QKV    48       // q: 0..15, k: 16..31, v: 32..47
#define NJ1       3        // n-tiles per wave, GEMM1 (16 waves * 3 = 48)
#define TT        4        // token-tiles of 16 (64 tokens)

typedef _Float16 f16x8 __attribute__((ext_vector_type(8)));
typedef _Float16 f16x4 __attribute__((ext_vector_type(4)));
typedef _Float16 f16x2 __attribute__((ext_vector_type(2)));
typedef float    f32x4 __attribute__((ext_vector_type(4)));

static __device__ __forceinline__ f16x2 pkrtz(float a, float b) {
    return (f16x2)__builtin_amdgcn_cvt_pkrtz(a, b);
}

// ---------------------------------------------------------------------------
// Prep: pack Wq|Wk|Wv and Wp into MFMA A-operand fragment order, fp32->f16.
// frag[j] = W[kt*32 + quad*8 + j][nt*16 + (lane&15)]
// packed index u = (nt*KT + kt)*64 + lane ; 8 f16 (16 B) per u, contiguous.
// ---------------------------------------------------------------------------
__global__ void pack_weights(const float* __restrict__ Wq,
                             const float* __restrict__ Wk,
                             const float* __restrict__ Wv,
                             const float* __restrict__ Wp,
                             _Float16* __restrict__ pk)
{
    const int QKV_FRAGS = NT_QKV * KT * 64;   // 24576
    int u = blockIdx.x * blockDim.x + threadIdx.x;  // 0..32767
    const float* W;
    int nt, kt, lane;
    if (u < QKV_FRAGS) {
        nt = u / (KT * 64); kt = (u / 64) % KT; lane = u % 64;
        if (nt < 16)      { W = Wq; }
        else if (nt < 32) { W = Wk; nt -= 16; }
        else              { W = Wv; nt -= 32; }
    } else {
        int u2 = u - QKV_FRAGS;
        nt = u2 / (KT * 64); kt = (u2 / 64) % KT; lane = u2 % 64;
        W = Wp;
    }
    const int n  = nt * 16 + (lane & 15);
    const int k0 = kt * 32 + (lane >> 4) * 8;
    f16x8 frag;
#pragma unroll
    for (int j = 0; j < 8; ++j)
        frag[j] = (_Float16)W[(size_t)(k0 + j) * DIMX + n];
    *(f16x8*)(pk + (size_t)u * 8) = frag;
}

// ---------------------------------------------------------------------------
// Main fused kernel. LDS: V (64x264 f16: v tile, later x tile) + QKV (64x776).
// ---------------------------------------------------------------------------
__global__ __launch_bounds__(NTHREADS, 4)   // 4 waves/EU, VGPR<=128, 1 blk/CU
void fused_attn_mfma(const float* __restrict__ v,
                     const _Float16* __restrict__ Wqkv_pk,
                     const _Float16* __restrict__ Wp_pk,
                     const float* __restrict__ bp,
                     float* __restrict__ out)
{
    __shared__ __align__(16) _Float16 S[TM * VSTRIDE + TM * QSTRIDE]; // 133120 B
    _Float16* V   = S;                      // v tile, later x tile
    _Float16* QKV = S + TM * VSTRIDE;       // q[0:256) k[256:512) vv[512:768)

    const int tid   = threadIdx.x;
    const int lane  = tid & 63;
    const int wv_id = tid >> 6;      // wave 0..15
    const int l15   = lane & 15;
    const int quad  = lane >> 4;
    const long token0 = (long)blockIdx.x * TM;

    // ---- stage 0: v tile fp32 -> f16 -> V (row-major, stride 264) ----------
    {
        const float4* src = (const float4*)(v + token0 * DIMX);
#pragma unroll
        for (int i = 0; i < 4; ++i) {
            int u = tid + NTHREADS * i;       // 0..4095 float4 slots
            int m = u >> 6;                   // token row 0..63
            int c = (u & 63) * 4;
            float4 t4 = src[u];
            f16x2 lo = pkrtz(t4.x, t4.y), hi = pkrtz(t4.z, t4.w);
            f16x4 b4 = { lo.x, lo.y, hi.x, hi.y };
            *(f16x4*)&V[m * VSTRIDE + c] = b4;
        }
    }
    __syncthreads();                                    // barrier 1

    // ---- GEMM1: single pass; wave w owns n-tiles {3w, 3w+1, 3w+2} ----------
    {
        const int t0 = wv_id * NJ1;
        f32x4 acc[TT][NJ1];
#pragma unroll
        for (int tt = 0; tt < TT; ++tt)
#pragma unroll
            for (int j = 0; j < NJ1; ++j)
                acc[tt][j] = (f32x4){0.f, 0.f, 0.f, 0.f};

        const f16x8* wb = (const f16x8*)Wqkv_pk + lane;
        // depth-2 weight prefetch
        f16x8 w0[NJ1], w1[NJ1];
#pragma unroll
        for (int j = 0; j < NJ1; ++j) {
            w0[j] = wb[(size_t)((t0 + j) * KT + 0) * 64];
            w1[j] = wb[(size_t)((t0 + j) * KT + 1) * 64];
        }
        for (int kt = 0; kt < KT; ++kt) {
            const int ktp = (kt + 2 < KT) ? kt + 2 : KT - 1;
            f16x8 wn[NJ1];
#pragma unroll
            for (int j = 0; j < NJ1; ++j)
                wn[j] = wb[(size_t)((t0 + j) * KT + ktp) * 64];

            f16x8 vf[TT];
#pragma unroll
            for (int tt = 0; tt < TT; ++tt)
                vf[tt] = *(const f16x8*)&V[(tt * 16 + l15) * VSTRIDE + kt * 32 + quad * 8];

#pragma unroll
            for (int j = 0; j < NJ1; ++j)
#pragma unroll
                for (int tt = 0; tt < TT; ++tt)
                    acc[tt][j] = __builtin_amdgcn_mfma_f32_16x16x32_f16(w0[j], vf[tt], acc[tt][j], 0, 0, 0);

#pragma unroll
            for (int j = 0; j < NJ1; ++j) { w0[j] = w1[j]; w1[j] = wn[j]; }
        }
        // immediate writeback (QKV region is disjoint from V region)
#pragma unroll
        for (int tt = 0; tt < TT; ++tt)
#pragma unroll
            for (int j = 0; j < NJ1; ++j) {
                f16x2 a = pkrtz(acc[tt][j][0], acc[tt][j][1]);
                f16x2 b = pkrtz(acc[tt][j][2], acc[tt][j][3]);
                f16x4 p4 = { a.x, a.y, b.x, b.y };
                *(f16x4*)&QKV[(tt * 16 + l15) * QSTRIDE + (t0 + j) * 16 + quad * 4] = p4;
            }
    }
    __syncthreads();                                    // barrier 2

    // ---- attention: 16 threads/token = (head h, half d0); packed f16 -------
    {
        const int ta  = tid >> 4;         // token 0..63
        const int sub = tid & 15;
        const int h   = sub >> 1;
        const int d0  = (sub & 1) * 16;   // half of the 32-wide head dim
        const float scale = 0.17677669529663687f;  // 32^-0.5

        const _Float16* qrow  = &QKV[ta * QSTRIDE + h * HD + d0];
        const _Float16* kbase = &QKV[ta * QSTRIDE + 256 + d0];
        const _Float16* vbase = &QKV[ta * QSTRIDE + 512 + d0];

        f16x8 q0 = *(const f16x8*)qrow;
        f16x8 q1 = *(const f16x8*)(qrow + 8);

        float logits[NH];
#pragma unroll
        for (int g = 0; g < NH; ++g) {
            f16x8 k0 = *(const f16x8*)(kbase + g * HD);
            f16x8 k1 = *(const f16x8*)(kbase + g * HD + 8);
            f16x8 p  = q0 * k0;
            p += q1 * k1;
            f16x4 r4 = __builtin_shufflevector(p, p, 0, 1, 2, 3)
                     + __builtin_shufflevector(p, p, 4, 5, 6, 7);
            f16x2 r2 = __builtin_shufflevector(r4, r4, 0, 1)
                     + __builtin_shufflevector(r4, r4, 2, 3);
            logits[g] = (float)r2.x + (float)r2.y;
        }
#pragma unroll
        for (int g = 0; g < NH; ++g)
            logits[g] = (logits[g] + __shfl_xor(logits[g], 1, 64)) * scale;

        float mx = logits[0];
#pragma unroll
        for (int g = 1; g < NH; ++g) mx = fmaxf(mx, logits[g]);
        float se = 0.f;
#pragma unroll
        for (int g = 0; g < NH; ++g) { logits[g] = __expf(logits[g] - mx); se += logits[g]; }
        float inv = 1.f / se;

        f16x8 xa0 = (f16x8)(_Float16)0.f;
        f16x8 xa1 = (f16x8)(_Float16)0.f;
#pragma unroll
        for (int g = 0; g < NH; ++g) {
            _Float16 ph = (_Float16)(logits[g] * inv);
            f16x8 pw = { ph, ph, ph, ph, ph, ph, ph, ph };
            f16x8 v0 = *(const f16x8*)(vbase + g * HD);
            f16x8 v1 = *(const f16x8*)(vbase + g * HD + 8);
            xa0 += pw * v0;
            xa1 += pw * v1;
        }
        // write x into V region (disjoint from QKV; V-tile reads all finished
        // before barrier 2)
        *(f16x8*)&V[ta * VSTRIDE + h * HD + d0]     = xa0;
        *(f16x8*)&V[ta * VSTRIDE + h * HD + d0 + 8] = xa1;
    }
    __syncthreads();                                    // barrier 3

    // ---- GEMM2: out = x @ Wp + bp; wave w owns n-tile w --------------------
    {
        const int nt = wv_id;
        f32x4 acc[TT];
#pragma unroll
        for (int tt = 0; tt < TT; ++tt)
            acc[tt] = (f32x4){0.f, 0.f, 0.f, 0.f};

        const f16x8* wb = (const f16x8*)Wp_pk + lane;
        f16x8 w0 = wb[(size_t)(nt * KT + 0) * 64];
        f16x8 w1 = wb[(size_t)(nt * KT + 1) * 64];

        for (int kt = 0; kt < KT; ++kt) {
            const int ktp = (kt + 2 < KT) ? kt + 2 : KT - 1;
            f16x8 wn = wb[(size_t)(nt * KT + ktp) * 64];

            f16x8 xf[TT];
#pragma unroll
            for (int tt = 0; tt < TT; ++tt)
                xf[tt] = *(const f16x8*)&V[(tt * 16 + l15) * VSTRIDE + kt * 32 + quad * 8];

#pragma unroll
            for (int tt = 0; tt < TT; ++tt)
                acc[tt] = __builtin_amdgcn_mfma_f32_16x16x32_f16(w0, xf[tt], acc[tt], 0, 0, 0);

            w0 = w1; w1 = wn;
        }
        f32x4 b = *(const f32x4*)&bp[nt * 16 + quad * 4];
#pragma unroll
        for (int tt = 0; tt < TT; ++tt) {
            f32x4 o = acc[tt] + b;
            *(f32x4*)&out[(token0 + tt * 16 + l15) * DIMX + nt * 16 + quad * 4] = o;
        }
    }
}

extern "C" void kernel_launch(void* const* d_in, const int* in_sizes, int n_in,
                              void* d_out, int out_size, void* d_ws, size_t ws_size,
                              hipStream_t stream) {
    const float* v  = (const float*)d_in[0];
    const float* Wq = (const float*)d_in[1];
    const float* Wk = (const float*)d_in[2];
    const float* Wv = (const float*)d_in[3];
    const float* Wp = (const float*)d_in[4];
    const float* bp = (const float*)d_in[5];
    float* out = (float*)d_out;

    _Float16* pk = (_Float16*)d_ws;                // 32768 frags * 16 B = 512 KB
    const _Float16* Wqkv_pk = pk;                  // 24576 frags
    const _Float16* Wp_pk   = pk + (size_t)24576 * 8;

    pack_weights<<<256, 128, 0, stream>>>(Wq, Wk, Wv, Wp, pk);

    const int ntokens = in_sizes[0] / DIMX;        // 65536
    fused_attn_mfma<<<ntokens / TM, NTHREADS, 0, stream>>>(v, Wqkv_pk, Wp_pk, bp, out);
}